// Round 5
// baseline (355.814 us; speedup 1.0000x reference)
//
#include <hip/hip_runtime.h>
#include <stdint.h>

// SO3Conv mapped per l to GEMM: C[(b,m),(g,v)] = A[(b,m),(u,f)] * B[(u,f),(g,v)]
//   A: pre-transposed x, bf16, row-major [M=1024d][K=64d], k = u*64+f
//   B: psi with both norms folded, bf16, B-operand layout Bt[n=(g*d+v)][k], rows padded to 128-mult with 0
// Workspace: A buffers then B buffers, ~63.8 MB.
// R1: double-buffer + XOR swizzle (bank conflicts 5.3M -> 0, dur flat -> latency-bound confirmed).
// R2/R3: 3-deep counted-vmcnt pipeline: 132 -> 116.5us, MfmaUtil 15%. Per-iter lgkm full-drain +
//     2nd barrier + sched pins exposed ds_read latency (m141 lesson).
// R4: 4-buffer single-barrier variant; container died (R2 also; R3 passed -> infra suspected but
//     de-risking anyway).
// R5: 3-buffer depth-2 single-barrier pipeline, 48KB LDS (R3's passed envelope, 3 blocks/CU).
//     Stage target (kt+2)%3 == (kt-1)%3 is safe without drains: any wave past barrier kt already
//     issued its kt-1 MFMAs, whose compiler-inserted lgkmcnt waits retired the kt-1 ds_reads.

typedef __bf16 bf16x8 __attribute__((ext_vector_type(8)));
typedef float floatx4 __attribute__((ext_vector_type(4)));

#define XROW 29120   // 64*455

__device__ __forceinline__ unsigned short f2bf(float f) {
  union { float f; unsigned int u; } c; c.f = f;
  unsigned int u = c.u;
  return (unsigned short)((u + 0x7FFFu + ((u >> 16) & 1u)) >> 16);
}
__device__ __forceinline__ unsigned int pack2(float a, float b) {
  return (unsigned int)f2bf(a) | ((unsigned int)f2bf(b) << 16);
}

__host__ __device__ constexpr int d_of(int L) { return 2 * L + 1; }
__host__ __device__ constexpr int off_of(int L) { int s = 0; for (int i = 0; i < L; ++i) s += d_of(i) * d_of(i); return s; }
__host__ __device__ constexpr size_t a_off(int L) { size_t s = 0; for (int i = 0; i < L; ++i) s += (size_t)65536 * d_of(i) * d_of(i); return s; }
__host__ __device__ constexpr size_t b_off(int L) { size_t s = a_off(7); for (int i = 0; i < L; ++i) s += (size_t)4096 * d_of(i) * (d_of(i) + 1); return s; }

// ---------------- Kernel 1 (fused): build B (blocks 0..447) + transpose x (blocks 448..1471) ----------------
__global__ __launch_bounds__(256) void prep(const float* __restrict__ x, const float* __restrict__ Dm,
                                            const float* __restrict__ w, unsigned short* __restrict__ ws) {
  __shared__ __align__(16) float smem[64 * 68 + 64 * 172];   // 60 KB: build uses both halves, transpose first 43.3KB
  const int tid = threadIdx.x;
  const int bid = blockIdx.x;

  if (bid < 448) {
    // ---- build B: psi[f,g,r] = sum_n w[f,g,n] D[n,off+r], norms folded, 4x4 register tiling ----
    float* wg = smem;              // [64][68]: wg[n][f]
    float* Dl = smem + 64 * 68;    // [64][172]: Dl[n][r], zero-padded to r<172
    const int g = bid & 63, l = bid >> 6;
    const int d = 2 * l + 1, d2 = d * d, K = 64 * d;
    int off = 0; size_t boff = a_off(7);
    for (int i = 0; i < l; ++i) { int dd = 2 * i + 1; off += dd * dd; boff += (size_t)4096 * dd * (dd + 1); }
    unsigned short* B = ws + boff;

    for (int t = tid; t < 4096; t += 256) {
      int n = t & 63, f = t >> 6;
      wg[n * 68 + f] = w[(size_t)f * 4096 + g * 64 + n];
    }
    for (int t = tid; t < 64 * 172; t += 256) {
      int n = t / 172, r = t - n * 172;
      Dl[t] = (r < d2) ? Dm[n * 455 + off + r] : 0.f;
    }
    __syncthreads();

    const float sl = 1.0f / (64.0f * sqrtf((float)d));
    const int RT = (d2 + 3) >> 2;
    for (int tt = tid; tt < 16 * RT; tt += 256) {
      const int ft = tt & 15, rt = tt >> 4;
      float acc[4][4] = {};
      for (int n = 0; n < 64; ++n) {
        floatx4 wv = *(const floatx4*)(wg + n * 68 + ft * 4);
        floatx4 dv = *(const floatx4*)(Dl + n * 172 + rt * 4);
#pragma unroll
        for (int a = 0; a < 4; ++a)
#pragma unroll
          for (int b2 = 0; b2 < 4; ++b2) acc[a][b2] += wv[a] * dv[b2];
      }
#pragma unroll
      for (int b2 = 0; b2 < 4; ++b2) {
        int r = rt * 4 + b2;
        if (r < d2) {
          int u = r / d, v = r - u * d;
          size_t base = (size_t)(g * d + v) * K + u * 64 + ft * 4;
#pragma unroll
          for (int a = 0; a < 4; ++a) B[base + a] = f2bf(acc[a][b2] * sl);
        }
      }
    }
    { // zero one pad row per g (rows 64d..64d+63 across the 64 g-blocks)
      int nn = 64 * d + g;
      for (int k = tid; k < K; k += 256) B[(size_t)nn * K + k] = 0;
    }
  } else {
    // ---- transpose x -> A (bf16, pair-packed 4B stores) ----
    float* xs = smem;
    const int b = bid - 448;
    const float* xb = x + (size_t)b * XROW;
    size_t aoff = 0;

    // phase A: l0..l4 (cols 0..165)
    for (int t = tid; t < 64 * 165; t += 256) { int f = t / 165, c = t - f * 165; xs[t] = xb[(size_t)f * 455 + c]; }
    __syncthreads();
    int off = 0;
#pragma unroll
    for (int l = 0; l < 5; ++l) {
      const int d = 2 * l + 1, d2 = d * d, n1 = 64 * d2;
      unsigned int* A = (unsigned int*)(ws + aoff + (size_t)b * n1);
      for (int t = tid; t < (n1 >> 1); t += 256) {
        int f2 = t & 31, s = t >> 5;
        int u = s % d, m = s / d;
        int c = off + u * d + m;
        A[t] = pack2(xs[(2 * f2) * 165 + c], xs[(2 * f2 + 1) * 165 + c]);
      }
      off += d2; aoff += (size_t)1024 * n1;
    }
    __syncthreads();
    // phase B: l5 (cols 165..286)
    for (int t = tid; t < 64 * 121; t += 256) { int f = t / 121, c = t - f * 121; xs[t] = xb[(size_t)f * 455 + 165 + c]; }
    __syncthreads();
    {
      const int n1 = 64 * 121;
      unsigned int* A = (unsigned int*)(ws + aoff + (size_t)b * n1);
      for (int t = tid; t < (n1 >> 1); t += 256) {
        int f2 = t & 31, s = t >> 5;
        int u = s % 11, m = s / 11;
        int c = u * 11 + m;
        A[t] = pack2(xs[(2 * f2) * 121 + c], xs[(2 * f2 + 1) * 121 + c]);
      }
      aoff += (size_t)1024 * n1;
    }
    __syncthreads();
    // phase C: l6 (cols 286..455)
    for (int t = tid; t < 64 * 169; t += 256) { int f = t / 169, c = t - f * 169; xs[t] = xb[(size_t)f * 455 + 286 + c]; }
    __syncthreads();
    {
      const int n1 = 64 * 169;
      unsigned int* A = (unsigned int*)(ws + aoff + (size_t)b * n1);
      for (int t = tid; t < (n1 >> 1); t += 256) {
        int f2 = t & 31, s = t >> 5;
        int u = s % 13, m = s / 13;
        int c = u * 13 + m;
        A[t] = pack2(xs[(2 * f2) * 169 + c], xs[(2 * f2 + 1) * 169 + c]);
      }
    }
  }
}

// ---------------- Kernel 2: fused all-l MFMA GEMM, 3-buffer depth-2 single-barrier pipeline ----------------
__device__ __forceinline__ void async_copy16(const void* gp, void* lp) {
  __builtin_amdgcn_global_load_lds((__attribute__((address_space(1))) void*)gp,
                                   (__attribute__((address_space(3))) void*)lp, 16, 0, 0);
}

template <int N>
__device__ __forceinline__ void wait_vmcnt() {
  asm volatile("s_waitcnt vmcnt(%0)" :: "n"(N) : "memory");
}

template <int L>
__device__ __forceinline__ void gemm_body(int local, const unsigned short* __restrict__ ws,
                                          float* __restrict__ out,
                                          unsigned short* As, unsigned short* Bs) {
  constexpr int d = 2 * L + 1;
  constexpr int K = 64 * d;
  constexpr int NT = (d + 1) / 2;          // N-tiles of 128 (N padded to 64*(d+1)); M-tiles = 8d
  constexpr int OFF = off_of(L);
  constexpr int KT = 2 * d;                // 32-wide k-steps
  const unsigned short* A = ws + a_off(L);
  const unsigned short* B = ws + b_off(L);
  // XCD swizzle: blocks sharing an A M-tile are blockIdx stride-8 apart -> same XCD (round-robin).
  const int x8 = local & 7, tt = local >> 3;
  const int mt = (tt / NT) * 8 + x8;
  const int nt = tt % NT;
  const int tid = threadIdx.x;
  const int w = tid >> 6, ln = tid & 63;
  const int wm = w >> 1, wn = w & 1;
  const int q = ln >> 4, r16 = ln & 15;

  // Staging: LDS dest linear (global_load_lds requirement); bank-conflict swizzle is
  // applied by permuting the 16B k-chunk in the GLOBAL source address: chunk ^= (row>>1)&3.
  const unsigned short* gp[4];
  unsigned short* ldst[4];
#pragma unroll
  for (int i = 0; i < 4; ++i) {
    int c = i * 256 + tid;
    if (i < 2) {
      int row = c >> 2, ch = (c & 3) ^ ((c >> 3) & 3);
      gp[i] = A + (size_t)(mt * 128 + row) * K + ch * 8;
      ldst[i] = As + (i * 256 + w * 64) * 8;
    } else {
      int c2 = c - 512;
      int row = c2 >> 2, ch = (c2 & 3) ^ ((c2 >> 3) & 3);
      gp[i] = B + (size_t)(nt * 128 + row) * K + ch * 8;
      ldst[i] = Bs + ((i - 2) * 256 + w * 64) * 8;
    }
  }

  // ds_read offsets with the matching XOR: stored chunk at slot (q^s) is global chunk q, s=(row>>1)&3
  const int sq = q ^ ((r16 >> 1) & 3);
  const int aoffs0 = (wm * 64 + r16) * 32 + sq * 8;
  const int boffs0 = (wn * 64 + r16) * 32 + sq * 8;

  floatx4 acc[4][4] = {};

  // prologue: issue 2 k-tiles (4 global_load_lds wave-insts each = 4 vmcnt ticks/tile)
#pragma unroll
  for (int t = 0; t < 2; ++t) {
    if (t < KT) {
#pragma unroll
      for (int i = 0; i < 4; ++i) { async_copy16(gp[i], ldst[i] + t * 4096); gp[i] += 32; }
    }
  }

#pragma unroll
  for (int kt = 0; kt < KT; ++kt) {
    // Wait for tile kt: at most 1 younger tile (4 loads) may remain in flight. Never 0 in steady state.
    if (kt < KT - 1) wait_vmcnt<4>();
    else             wait_vmcnt<0>();
    __builtin_amdgcn_s_barrier();            // tile kt resident for ALL waves
    __builtin_amdgcn_sched_barrier(0);       // nothing below may hoist above the rendezvous

    const unsigned short* Asc = As + (kt % 3) * 4096;
    const unsigned short* Bsc = Bs + (kt % 3) * 4096;
    bf16x8 af[4], bfr[4];
#pragma unroll
    for (int mi = 0; mi < 4; ++mi) af[mi] = *(const bf16x8*)(Asc + aoffs0 + mi * 512);
#pragma unroll
    for (int ni = 0; ni < 4; ++ni) bfr[ni] = *(const bf16x8*)(Bsc + boffs0 + ni * 512);

    if (kt + 2 < KT) {
      // buffer (kt+2)%3 == (kt-1)%3: safe — all waves past barrier kt have issued their kt-1 MFMAs,
      // whose compiler-inserted lgkmcnt waits retired the kt-1 ds_reads. No drain, no 2nd barrier.
#pragma unroll
      for (int i = 0; i < 4; ++i) { async_copy16(gp[i], ldst[i] + ((kt + 2) % 3) * 4096); gp[i] += 32; }
    }

#pragma unroll
    for (int mi = 0; mi < 4; ++mi)
#pragma unroll
      for (int ni = 0; ni < 4; ++ni)
        acc[mi][ni] = __builtin_amdgcn_mfma_f32_16x16x32_bf16(af[mi], bfr[ni], acc[mi][ni], 0, 0, 0);
    __builtin_amdgcn_sched_barrier(0);       // body stays inside the barrier interval (rule #18)
  }

#pragma unroll
  for (int ni = 0; ni < 4; ++ni) {
    int Cc = nt * 128 + wn * 64 + ni * 16 + r16;
    if (Cc < 64 * d) {
      int g = Cc / d, v = Cc - (Cc / d) * d;
#pragma unroll
      for (int mi = 0; mi < 4; ++mi) {
        int R0 = mt * 128 + wm * 64 + mi * 16 + q * 4;
#pragma unroll
        for (int reg = 0; reg < 4; ++reg) {
          int R = R0 + reg;
          int bb = R / d, m = R - (R / d) * d;
          out[(size_t)bb * XROW + g * 455 + OFF + v * d + m] = acc[mi][ni][reg];
        }
      }
    }
  }
}

__global__ __launch_bounds__(256) void gemm_all(const unsigned short* __restrict__ ws, float* __restrict__ out) {
  __shared__ alignas(16) unsigned short As[3 * 128 * 32];   // 3-deep: 24KB
  __shared__ alignas(16) unsigned short Bs[3 * 128 * 32];   // 3-deep: 24KB (48KB total -> 3 blocks/CU)
  // blocks per l: 4d(d+1) = {8,48,120,224,360,528,728}; cum {8,56,176,400,760,1288,2016}
  int b0 = 2015 - (int)blockIdx.x;   // longest-l blocks dispatch first
  if      (b0 <    8) gemm_body<0>(b0,        ws, out, As, Bs);
  else if (b0 <   56) gemm_body<1>(b0 -    8, ws, out, As, Bs);
  else if (b0 <  176) gemm_body<2>(b0 -   56, ws, out, As, Bs);
  else if (b0 <  400) gemm_body<3>(b0 -  176, ws, out, As, Bs);
  else if (b0 <  760) gemm_body<4>(b0 -  400, ws, out, As, Bs);
  else if (b0 < 1288) gemm_body<5>(b0 -  760, ws, out, As, Bs);
  else                gemm_body<6>(b0 - 1288, ws, out, As, Bs);
}

extern "C" void kernel_launch(void* const* d_in, const int* in_sizes, int n_in,
                              void* d_out, int out_size, void* d_ws, size_t ws_size,
                              hipStream_t stream) {
  const float* x = (const float*)d_in[0];
  const float* D = (const float*)d_in[1];
  const float* w = (const float*)d_in[2];
  float* out = (float*)d_out;
  unsigned short* ws = (unsigned short*)d_ws;   // ~63.8 MB

  hipLaunchKernelGGL(prep, dim3(1472), dim3(256), 0, stream, x, D, w, ws);
  hipLaunchKernelGGL(gemm_all, dim3(2016), dim3(256), 0, stream, ws, out);
}

// Round 6
// 344.136 us; speedup vs baseline: 1.0339x; 1.0339x over previous
//
#include <hip/hip_runtime.h>
#include <stdint.h>

// SO3Conv mapped per l to GEMM: C[(b,m),(g,v)] = A[(b,m),(u,f)] * B[(u,f),(g,v)]
//   A: pre-transposed x, bf16, row-major [M=1024d][K=64d], k = u*64+f
//   B: psi with both norms folded, bf16, B-operand layout Bt[n=(g*d+v)][k], rows padded to 128-mult with 0
// Workspace: A buffers then B buffers, ~63.8 MB.
// R1: double-buffer + XOR swizzle (bank conflicts 5.3M -> 0, dur flat).
// R3/R5: counted-vmcnt 3-buffer pipeline, with/without lgkm drains: both 116.5us, MfmaUtil 15%.
//     Totals accounting: matrix 18% + LDS 24% of wall -> overhead-dominated; sync micro-structure
//     exhausted. Per-wave 64x64 tile (8 reads : 16 MFMA) has a hard ~44% MfmaUtil ceiling and too
//     little work per barrier interval.
// R6: tile geometry: 256x128 block, 4 waves, wave-tile 128x64 (12 ds_read : 32 MFMA = 0.375KB/MFMA),
//     2x work per k-step, blocks 2016->1008. Pipeline/swizzle/prep identical to R5. 72KB LDS, 2 blk/CU.

typedef __bf16 bf16x8 __attribute__((ext_vector_type(8)));
typedef float floatx4 __attribute__((ext_vector_type(4)));

#define XROW 29120   // 64*455

__device__ __forceinline__ unsigned short f2bf(float f) {
  union { float f; unsigned int u; } c; c.f = f;
  unsigned int u = c.u;
  return (unsigned short)((u + 0x7FFFu + ((u >> 16) & 1u)) >> 16);
}
__device__ __forceinline__ unsigned int pack2(float a, float b) {
  return (unsigned int)f2bf(a) | ((unsigned int)f2bf(b) << 16);
}

__host__ __device__ constexpr int d_of(int L) { return 2 * L + 1; }
__host__ __device__ constexpr int off_of(int L) { int s = 0; for (int i = 0; i < L; ++i) s += d_of(i) * d_of(i); return s; }
__host__ __device__ constexpr size_t a_off(int L) { size_t s = 0; for (int i = 0; i < L; ++i) s += (size_t)65536 * d_of(i) * d_of(i); return s; }
__host__ __device__ constexpr size_t b_off(int L) { size_t s = a_off(7); for (int i = 0; i < L; ++i) s += (size_t)4096 * d_of(i) * (d_of(i) + 1); return s; }

// ---------------- Kernel 1 (fused): build B (blocks 0..447) + transpose x (blocks 448..1471) ----------------
__global__ __launch_bounds__(256) void prep(const float* __restrict__ x, const float* __restrict__ Dm,
                                            const float* __restrict__ w, unsigned short* __restrict__ ws) {
  __shared__ __align__(16) float smem[64 * 68 + 64 * 172];   // 60 KB: build uses both halves, transpose first 43.3KB
  const int tid = threadIdx.x;
  const int bid = blockIdx.x;

  if (bid < 448) {
    // ---- build B: psi[f,g,r] = sum_n w[f,g,n] D[n,off+r], norms folded, 4x4 register tiling ----
    float* wg = smem;              // [64][68]: wg[n][f]
    float* Dl = smem + 64 * 68;    // [64][172]: Dl[n][r], zero-padded to r<172
    const int g = bid & 63, l = bid >> 6;
    const int d = 2 * l + 1, d2 = d * d, K = 64 * d;
    int off = 0; size_t boff = a_off(7);
    for (int i = 0; i < l; ++i) { int dd = 2 * i + 1; off += dd * dd; boff += (size_t)4096 * dd * (dd + 1); }
    unsigned short* B = ws + boff;

    for (int t = tid; t < 4096; t += 256) {
      int n = t & 63, f = t >> 6;
      wg[n * 68 + f] = w[(size_t)f * 4096 + g * 64 + n];
    }
    for (int t = tid; t < 64 * 172; t += 256) {
      int n = t / 172, r = t - n * 172;
      Dl[t] = (r < d2) ? Dm[n * 455 + off + r] : 0.f;
    }
    __syncthreads();

    const float sl = 1.0f / (64.0f * sqrtf((float)d));
    const int RT = (d2 + 3) >> 2;
    for (int tt = tid; tt < 16 * RT; tt += 256) {
      const int ft = tt & 15, rt = tt >> 4;
      float acc[4][4] = {};
      for (int n = 0; n < 64; ++n) {
        floatx4 wv = *(const floatx4*)(wg + n * 68 + ft * 4);
        floatx4 dv = *(const floatx4*)(Dl + n * 172 + rt * 4);
#pragma unroll
        for (int a = 0; a < 4; ++a)
#pragma unroll
          for (int b2 = 0; b2 < 4; ++b2) acc[a][b2] += wv[a] * dv[b2];
      }
#pragma unroll
      for (int b2 = 0; b2 < 4; ++b2) {
        int r = rt * 4 + b2;
        if (r < d2) {
          int u = r / d, v = r - u * d;
          size_t base = (size_t)(g * d + v) * K + u * 64 + ft * 4;
#pragma unroll
          for (int a = 0; a < 4; ++a) B[base + a] = f2bf(acc[a][b2] * sl);
        }
      }
    }
    { // zero one pad row per g (rows 64d..64d+63 across the 64 g-blocks)
      int nn = 64 * d + g;
      for (int k = tid; k < K; k += 256) B[(size_t)nn * K + k] = 0;
    }
  } else {
    // ---- transpose x -> A (bf16, pair-packed 4B stores) ----
    float* xs = smem;
    const int b = bid - 448;
    const float* xb = x + (size_t)b * XROW;
    size_t aoff = 0;

    // phase A: l0..l4 (cols 0..165)
    for (int t = tid; t < 64 * 165; t += 256) { int f = t / 165, c = t - f * 165; xs[t] = xb[(size_t)f * 455 + c]; }
    __syncthreads();
    int off = 0;
#pragma unroll
    for (int l = 0; l < 5; ++l) {
      const int d = 2 * l + 1, d2 = d * d, n1 = 64 * d2;
      unsigned int* A = (unsigned int*)(ws + aoff + (size_t)b * n1);
      for (int t = tid; t < (n1 >> 1); t += 256) {
        int f2 = t & 31, s = t >> 5;
        int u = s % d, m = s / d;
        int c = off + u * d + m;
        A[t] = pack2(xs[(2 * f2) * 165 + c], xs[(2 * f2 + 1) * 165 + c]);
      }
      off += d2; aoff += (size_t)1024 * n1;
    }
    __syncthreads();
    // phase B: l5 (cols 165..286)
    for (int t = tid; t < 64 * 121; t += 256) { int f = t / 121, c = t - f * 121; xs[t] = xb[(size_t)f * 455 + 165 + c]; }
    __syncthreads();
    {
      const int n1 = 64 * 121;
      unsigned int* A = (unsigned int*)(ws + aoff + (size_t)b * n1);
      for (int t = tid; t < (n1 >> 1); t += 256) {
        int f2 = t & 31, s = t >> 5;
        int u = s % 11, m = s / 11;
        int c = u * 11 + m;
        A[t] = pack2(xs[(2 * f2) * 121 + c], xs[(2 * f2 + 1) * 121 + c]);
      }
      aoff += (size_t)1024 * n1;
    }
    __syncthreads();
    // phase C: l6 (cols 286..455)
    for (int t = tid; t < 64 * 169; t += 256) { int f = t / 169, c = t - f * 169; xs[t] = xb[(size_t)f * 455 + 286 + c]; }
    __syncthreads();
    {
      const int n1 = 64 * 169;
      unsigned int* A = (unsigned int*)(ws + aoff + (size_t)b * n1);
      for (int t = tid; t < (n1 >> 1); t += 256) {
        int f2 = t & 31, s = t >> 5;
        int u = s % 13, m = s / 13;
        int c = u * 13 + m;
        A[t] = pack2(xs[(2 * f2) * 169 + c], xs[(2 * f2 + 1) * 169 + c]);
      }
    }
  }
}

// ---------------- Kernel 2: fused all-l MFMA GEMM, 256x128 tile, wave-tile 128x64 (8x4 frags) ----------------
__device__ __forceinline__ void async_copy16(const void* gp, void* lp) {
  __builtin_amdgcn_global_load_lds((__attribute__((address_space(1))) void*)gp,
                                   (__attribute__((address_space(3))) void*)lp, 16, 0, 0);
}

template <int N>
__device__ __forceinline__ void wait_vmcnt() {
  asm volatile("s_waitcnt vmcnt(%0)" :: "n"(N) : "memory");
}

template <int L>
__device__ __forceinline__ void gemm_body(int local, const unsigned short* __restrict__ ws,
                                          float* __restrict__ out,
                                          unsigned short* As, unsigned short* Bs) {
  constexpr int d = 2 * L + 1;
  constexpr int K = 64 * d;
  constexpr int NT = (d + 1) / 2;          // N-tiles of 128 (N padded to 64*(d+1)); M-tiles of 256 = 4d
  constexpr int OFF = off_of(L);
  constexpr int KT = 2 * d;                // 32-wide k-steps
  const unsigned short* A = ws + a_off(L);
  const unsigned short* B = ws + b_off(L);
  // XCD-grouped dispatch: groups of 4 consecutive bids share the B-panel nt across 4 M-tiles.
  // blocks_l = 2d(d+1); /4 = d(d+1)/2 = d*NT (exact). mt = (tt/NT)*4 + x4, nt = tt%NT.
  const int x4 = local & 3, tt = local >> 2;
  const int mt = (tt / NT) * 4 + x4;
  const int nt = tt % NT;
  const int tid = threadIdx.x;
  const int w = tid >> 6, ln = tid & 63;
  const int wm = w >> 1, wn = w & 1;       // wave-tile: rows wm*128..+128, cols wn*64..+64
  const int q = ln >> 4, r16 = ln & 15;

  // Staging: LDS dest linear (global_load_lds requirement); bank-conflict swizzle applied by
  // permuting the 16B k-chunk in the GLOBAL source address: chunk ^= (row>>1)&3.
  // A-tile: 256 rows x 32 k = 16KB (4 insts); B-tile: 128 x 32 = 8KB (2 insts). 6 vmcnt ticks/tile.
  const unsigned short* gp[6];
  unsigned short* ldst[6];
#pragma unroll
  for (int i = 0; i < 6; ++i) {
    int c = i * 256 + tid;
    if (i < 4) {
      int row = c >> 2, ch = (c & 3) ^ ((c >> 3) & 3);
      gp[i] = A + (size_t)(mt * 256 + row) * K + ch * 8;
      ldst[i] = As + (i * 256 + w * 64) * 8;
    } else {
      int c2 = c - 1024;
      int row = c2 >> 2, ch = (c2 & 3) ^ ((c2 >> 3) & 3);
      gp[i] = B + (size_t)(nt * 128 + row) * K + ch * 8;
      ldst[i] = Bs + ((i - 4) * 256 + w * 64) * 8;
    }
  }

  // ds_read offsets with the matching XOR: stored chunk at slot (q^s) is global chunk q, s=(row>>1)&3
  const int sq = q ^ ((r16 >> 1) & 3);
  const int aoffs0 = (wm * 128 + r16) * 32 + sq * 8;   // af[mi] at +mi*512 (16 rows)
  const int boffs0 = (wn * 64 + r16) * 32 + sq * 8;    // bfr[ni] at +ni*512

  floatx4 acc[8][4] = {};

  // prologue: stage tiles 0,1 (6 global_load_lds each)
#pragma unroll
  for (int t = 0; t < 2; ++t) {
    if (t < KT) {
#pragma unroll
      for (int i = 0; i < 6; ++i) { async_copy16(gp[i], ldst[i] + t * (i < 4 ? 8192 : 4096)); gp[i] += 32; }
    }
  }

#pragma unroll
  for (int kt = 0; kt < KT; ++kt) {
    // Wait for tile kt: at most 1 younger tile (6 loads) in flight. Never 0 in steady state.
    if (kt < KT - 1) wait_vmcnt<6>();
    else             wait_vmcnt<0>();
    __builtin_amdgcn_s_barrier();            // tile kt resident for ALL waves
    __builtin_amdgcn_sched_barrier(0);       // nothing below may hoist above the rendezvous

    const unsigned short* Asc = As + (kt % 3) * 8192;
    const unsigned short* Bsc = Bs + (kt % 3) * 4096;
    bf16x8 af[8], bfr[4];
#pragma unroll
    for (int mi = 0; mi < 8; ++mi) af[mi] = *(const bf16x8*)(Asc + aoffs0 + mi * 512);
#pragma unroll
    for (int ni = 0; ni < 4; ++ni) bfr[ni] = *(const bf16x8*)(Bsc + boffs0 + ni * 512);

    if (kt + 2 < KT) {
      // buffer (kt+2)%3 == (kt-1)%3: safe — all waves past barrier kt have issued their kt-1 MFMAs,
      // whose compiler-inserted lgkmcnt waits retired the kt-1 ds_reads.
#pragma unroll
      for (int i = 0; i < 6; ++i) { async_copy16(gp[i], ldst[i] + ((kt + 2) % 3) * (i < 4 ? 8192 : 4096)); gp[i] += 32; }
    }

#pragma unroll
    for (int mi = 0; mi < 8; ++mi)
#pragma unroll
      for (int ni = 0; ni < 4; ++ni)
        acc[mi][ni] = __builtin_amdgcn_mfma_f32_16x16x32_bf16(af[mi], bfr[ni], acc[mi][ni], 0, 0, 0);
    __builtin_amdgcn_sched_barrier(0);       // body stays inside the barrier interval
  }

#pragma unroll
  for (int ni = 0; ni < 4; ++ni) {
    int Cc = nt * 128 + wn * 64 + ni * 16 + r16;
    if (Cc < 64 * d) {
      int g = Cc / d, v = Cc - (Cc / d) * d;
#pragma unroll
      for (int mi = 0; mi < 8; ++mi) {
        int R0 = mt * 256 + wm * 128 + mi * 16 + q * 4;
#pragma unroll
        for (int reg = 0; reg < 4; ++reg) {
          int R = R0 + reg;
          int bb = R / d, m = R - (R / d) * d;
          out[(size_t)bb * XROW + g * 455 + OFF + v * d + m] = acc[mi][ni][reg];
        }
      }
    }
  }
}

__global__ __launch_bounds__(256, 2) void gemm_all(const unsigned short* __restrict__ ws, float* __restrict__ out) {
  __shared__ alignas(16) unsigned short As[3 * 256 * 32];   // 3-deep: 48KB
  __shared__ alignas(16) unsigned short Bs[3 * 128 * 32];   // 3-deep: 24KB (72KB total -> 2 blocks/CU)
  // blocks per l: 2d(d+1) = {4,24,60,112,180,264,364}; cum {4,28,88,200,380,644,1008}
  int b0 = 1007 - (int)blockIdx.x;   // longest-l blocks dispatch first
  if      (b0 <    4) gemm_body<0>(b0,        ws, out, As, Bs);
  else if (b0 <   28) gemm_body<1>(b0 -    4, ws, out, As, Bs);
  else if (b0 <   88) gemm_body<2>(b0 -   28, ws, out, As, Bs);
  else if (b0 <  200) gemm_body<3>(b0 -   88, ws, out, As, Bs);
  else if (b0 <  380) gemm_body<4>(b0 -  200, ws, out, As, Bs);
  else if (b0 <  644) gemm_body<5>(b0 -  380, ws, out, As, Bs);
  else                gemm_body<6>(b0 -  644, ws, out, As, Bs);
}

extern "C" void kernel_launch(void* const* d_in, const int* in_sizes, int n_in,
                              void* d_out, int out_size, void* d_ws, size_t ws_size,
                              hipStream_t stream) {
  const float* x = (const float*)d_in[0];
  const float* D = (const float*)d_in[1];
  const float* w = (const float*)d_in[2];
  float* out = (float*)d_out;
  unsigned short* ws = (unsigned short*)d_ws;   // ~63.8 MB

  hipLaunchKernelGGL(prep, dim3(1472), dim3(256), 0, stream, x, D, w, ws);
  hipLaunchKernelGGL(gemm_all, dim3(1008), dim3(256), 0, stream, ws, out);
}